// Round 8
// baseline (108.551 us; speedup 1.0000x reference)
//
#include <hip/hip_runtime.h>

#define IN_F  4096
#define OUT_F 32000
#define KC    128          // k per tile
#define NT    (IN_F / KC)  // 32 tiles

typedef __attribute__((ext_vector_type(8))) short bf16x8;
typedef __attribute__((ext_vector_type(4))) float f32x4;
typedef unsigned int u32;

__device__ __forceinline__ short bf(float f) {
    __bf16 h = (__bf16)f;
    short s;
    __builtin_memcpy(&s, &h, 2);
    return s;
}

// HBM -> LDS direct (16B/lane). LDS dest = wave-uniform base + lane*16;
// per-lane global source carries the swizzle.
__device__ __forceinline__ void gload16(const void* g, void* l) {
    __builtin_amdgcn_global_load_lds(
        (const __attribute__((address_space(1))) u32*)g,
        (__attribute__((address_space(3))) u32*)l, 16, 0, 0);
}

// W-row swizzle (verified in R7): fragment ds_read_b128 pairs land 8
// accesses on every one of the 32 banks (conflict-free minimum).
__device__ __forceinline__ int swzW(int r) {
    return ((r & 7) << 5) | (((r >> 3) & 1) << 4);
}

// Block = 256 threads (4 waves), 64 out-ch x 16 batch. ZERO BARRIERS:
//  - W staging is wave-private (wave w loads/consumes rows [16w,16w+16))
//    via global_load_lds into its own quarter of Wl, double-buffered.
//  - X is never in LDS: each lane loads its MFMA B-fragment floats
//    directly from global (L2-resident, 8 small loads/wave/tile).
// Depth-2 pipeline with hand-counted vmcnt: per-tile issue group =
// 8 W gloads + 8 X loads = 16 VMEM ops; "s_waitcnt vmcnt(16)" at tile t
// retires exactly group(t) while group(t+1) stays in flight. The
// compiler-forced vmcnt(0)-before-barrier drain (the ~15-20% stall of
// all prior rounds) is gone because there are no barriers.
__global__ __launch_bounds__(256) void w8a16_kernel(
    const int* __restrict__ W, const float* __restrict__ X,
    const float* __restrict__ scale, const float* __restrict__ bias,
    float* __restrict__ out)
{
    __shared__ __align__(16) int Wl[2][64][KC];   // 64 KB raw int32

    const int tid  = threadIdx.x;
    const int lane = tid & 63;
    const int wave = tid >> 6;
    const int n    = lane & 15;   // MFMA: A row (out-ch) / B row (batch)
    const int kg   = lane >> 4;   // MFMA k-group
    const int lo   = lane & 31;   // staging: 16-B quad within 512-B chunk
    const int hi   = lane >> 5;   // staging: row parity within instr
    const int o_base = blockIdx.x * 64;

    float4 xrA[8], xrB[8];        // raw X fragments, two tile sets (static names)
    f32x4  acc = {0.f, 0.f, 0.f, 0.f};

    const int rA   = wave * 16 + n;
    const int swzA = swzW(rA);

    // ---- 8 x 1KB W gloads (wave-private rows) ----
    #define GLOADW(buf, t)                                                        \
        _Pragma("unroll")                                                         \
        for (int j = 0; j < 8; ++j) {                                             \
            const int r = wave * 16 + 2 * j + hi;                                 \
            const char* gp = (const char*)W                                       \
                + ((size_t)(o_base + r) * IN_F + (size_t)(t) * KC) * 4            \
                + ((lo * 16) ^ swzW(r));                                          \
            gload16(gp, &Wl[buf][wave * 16 + 2 * j][0]);                          \
        }

    // ---- 8 x dwordx4 X fragment loads, straight into MFMA layout ----
    #define LOADX(XR, t)                                                          \
        _Pragma("unroll")                                                         \
        for (int s = 0; s < 4; ++s) {                                             \
            const float* xp = X + (size_t)n * IN_F + (t) * KC + s * 32 + kg * 8;  \
            XR[2*s]   = *reinterpret_cast<const float4*>(xp);                     \
            XR[2*s+1] = *reinterpret_cast<const float4*>(xp + 4);                 \
        }

    // ---- one tile: wait group(t), ds_read W, cvt X, fence, issue group(t+2),
    //      cvt W + 4 MFMAs ----
    #define BODY(buf, XR, VMS, DOISS, tnext)                                      \
    {                                                                             \
        asm volatile("s_waitcnt vmcnt(" VMS ")" ::: "memory");                    \
        __builtin_amdgcn_sched_barrier(0);                                        \
        const char* wbase = (const char*)&Wl[buf][rA][0];                         \
        int4 q[8];                                                                \
        _Pragma("unroll")                                                         \
        for (int s = 0; s < 4; ++s) {                                             \
            const int o0 = (s * 128 + kg * 32) ^ swzA;                            \
            q[2*s]   = *reinterpret_cast<const int4*>(wbase + o0);                \
            q[2*s+1] = *reinterpret_cast<const int4*>(wbase + (o0 ^ 16));         \
        }                                                                         \
        bf16x8 B[4];                                                              \
        _Pragma("unroll")                                                         \
        for (int s = 0; s < 4; ++s) {                                             \
            B[s][0]=bf(XR[2*s].x);   B[s][1]=bf(XR[2*s].y);                       \
            B[s][2]=bf(XR[2*s].z);   B[s][3]=bf(XR[2*s].w);                       \
            B[s][4]=bf(XR[2*s+1].x); B[s][5]=bf(XR[2*s+1].y);                     \
            B[s][6]=bf(XR[2*s+1].z); B[s][7]=bf(XR[2*s+1].w);                     \
        }                                                                         \
        asm volatile("s_waitcnt lgkmcnt(0)" ::: "memory");                        \
        __builtin_amdgcn_sched_barrier(0);                                        \
        if (DOISS) { GLOADW(buf, tnext); LOADX(XR, tnext); }                      \
        _Pragma("unroll")                                                         \
        for (int s = 0; s < 4; ++s) {                                             \
            bf16x8 a;                                                             \
            a[0]=bf((float)q[2*s].x);   a[1]=bf((float)q[2*s].y);                 \
            a[2]=bf((float)q[2*s].z);   a[3]=bf((float)q[2*s].w);                 \
            a[4]=bf((float)q[2*s+1].x); a[5]=bf((float)q[2*s+1].y);               \
            a[6]=bf((float)q[2*s+1].z); a[7]=bf((float)q[2*s+1].w);               \
            acc = __builtin_amdgcn_mfma_f32_16x16x32_bf16(a, B[s], acc, 0, 0, 0); \
        }                                                                         \
    }

    // ---- prologue: groups 0 and 1 in flight (ordered by sched_barrier) ----
    GLOADW(0, 0); LOADX(xrA, 0);
    __builtin_amdgcn_sched_barrier(0);
    GLOADW(1, 1); LOADX(xrB, 1);

    // ---- main loop: tiles 0..NT-3, each body issues group(t+2) ----
    for (int t = 0; t < NT - 2; t += 2) {
        BODY(0, xrA, "16", 1, t + 2);
        BODY(1, xrB, "16", 1, t + 3);
    }
    // ---- tail: tiles NT-2, NT-1 (nothing left to issue) ----
    BODY(0, xrA, "16", 0, 0);
    BODY(1, xrB, "0",  0, 0);

    // ---- epilogue: D col = lane&15 (batch n), row = kg*4 + reg (out-ch) ----
    const int o = o_base + wave * 16 + kg * 4;
    const float4 sc = *reinterpret_cast<const float4*>(scale + o);
    const float4 bs = *reinterpret_cast<const float4*>(bias + o);
    float4 rr;
    rr.x = acc[0] * sc.x + bs.x;
    rr.y = acc[1] * sc.y + bs.y;
    rr.z = acc[2] * sc.z + bs.z;
    rr.w = acc[3] * sc.w + bs.w;
    *reinterpret_cast<float4*>(out + (size_t)n * OUT_F + o) = rr;

    #undef GLOADW
    #undef LOADX
    #undef BODY
}

extern "C" void kernel_launch(void* const* d_in, const int* in_sizes, int n_in,
                              void* d_out, int out_size, void* d_ws, size_t ws_size,
                              hipStream_t stream) {
    const float* x     = (const float*)d_in[0];
    const int*   w     = (const int*)  d_in[1];   // int8 values widened to int32 by harness
    const float* scale = (const float*)d_in[2];
    const float* bias  = (const float*)d_in[3];
    float* out = (float*)d_out;
    (void)in_sizes; (void)n_in; (void)d_ws; (void)ws_size; (void)out_size;

    w8a16_kernel<<<dim3(OUT_F / 64), dim3(256), 0, stream>>>(w, x, scale, bias, out);
}

// Round 10
// 104.310 us; speedup vs baseline: 1.0407x; 1.0407x over previous
//
#include <hip/hip_runtime.h>

#define IN_F  4096
#define OUT_F 32000
#define KC    128          // k per tile
#define NT    (IN_F / KC)  // 32 tiles

typedef __attribute__((ext_vector_type(8))) short bf16x8;
typedef __attribute__((ext_vector_type(4))) float f32x4;
typedef unsigned int u32;

__device__ __forceinline__ short bf(float f) {
    __bf16 h = (__bf16)f;
    short s;
    __builtin_memcpy(&s, &h, 2);
    return s;
}

// HBM -> LDS direct (16B/lane). LDS dest = wave-uniform base + lane*16;
// per-lane global source carries the swizzle. (Proven in R7.)
__device__ __forceinline__ void gload16(const void* g, void* l) {
    __builtin_amdgcn_global_load_lds(
        (const __attribute__((address_space(1))) u32*)g,
        (__attribute__((address_space(3))) u32*)l, 16, 0, 0);
}

// W-row swizzle (R7-verified): fragment ds_read_b128 pairs land 8 accesses
// on every one of the 32 banks (conflict-free minimum).
__device__ __forceinline__ int swzW(int r) {
    return ((r & 7) << 5) | (((r >> 3) & 1) << 4);
}

#define SBAR() __builtin_amdgcn_sched_barrier(0)

// R7 structure EXACTLY (4 waves, 64 out-ch x 16 batch, W via global_load_lds
// double-buffered 64KB, X reg-staged -> bf16 LDS 8KB) with ONE change:
// __syncthreads() [which forces s_waitcnt vmcnt(0) -- draining the 8 W
// prefetch loads every tile] is replaced by raw s_barrier + hand-counted
// vmcnt (m201 pattern). Per-tile VMEM group = 2 X loads then 8 W gloads:
//   entry in-flight: W(t)=8
//   issue group(t+1): -> 18
//   vmcnt(10): retire W(t)   (Wl[cur] complete; wave-private so own count ok)
//   COMPUTE(cur)
//   vmcnt(8):  retire X(t+1) (xreg valid; W(t+1) 8 stay in flight)
//   XWRITE -> lgkmcnt(0) -> s_barrier   [8 loads IN FLIGHT across barrier]
__global__ __launch_bounds__(256) void w8a16_kernel(
    const int* __restrict__ W, const float* __restrict__ X,
    const float* __restrict__ scale, const float* __restrict__ bias,
    float* __restrict__ out)
{
    __shared__ __align__(16) int   Wl[2][64][KC];  // raw int32, 64 KB
    __shared__ __align__(16) short Xl[2][16][KC];  // bf16, 8 KB

    const int tid  = threadIdx.x;
    const int lane = tid & 63;
    const int wave = tid >> 6;
    const int n    = lane & 15;   // MFMA: A row (out-ch) / B row (batch)
    const int kg   = lane >> 4;   // MFMA k-group
    const int lo   = lane & 31;   // staging: 16-B quad within 512-B chunk
    const int hi   = lane >> 5;   // staging: row parity within instr
    const int o_base = blockIdx.x * 64;

    float4 xreg[2];
    f32x4  acc = {0.f, 0.f, 0.f, 0.f};

    #define LOADX(t)                                                              \
        _Pragma("unroll")                                                         \
        for (int j = 0; j < 2; ++j) {                                             \
            const int r = wave * 4 + 2 * j + hi;                                  \
            xreg[j] = *reinterpret_cast<const float4*>(                           \
                X + (size_t)r * IN_F + (t) * KC + lo * 4);                        \
        }

    #define GLOADW(buf, t)                                                        \
        _Pragma("unroll")                                                         \
        for (int j = 0; j < 8; ++j) {                                             \
            const int r  = wave * 16 + 2 * j + hi;                                \
            const char* gp = (const char*)W                                       \
                + ((size_t)(o_base + r) * IN_F + (size_t)(t) * KC) * 4            \
                + ((lo * 16) ^ swzW(r));                                          \
            gload16(gp, &Wl[buf][wave * 16 + 2 * j][0]);                          \
        }

    #define XWRITE(buf)                                                           \
        _Pragma("unroll")                                                         \
        for (int j = 0; j < 2; ++j) {                                             \
            const int r = wave * 4 + 2 * j + hi;                                  \
            short4 v;                                                             \
            v.x = bf(xreg[j].x); v.y = bf(xreg[j].y);                             \
            v.z = bf(xreg[j].z); v.w = bf(xreg[j].w);                             \
            char* p = (char*)&Xl[buf][r][0] + ((lo * 8) ^ ((r & 7) << 4));        \
            *reinterpret_cast<short4*>(p) = v;                                    \
        }

    const int rA    = wave * 16 + n;
    const int swzA  = swzW(rA);
    const int swzAx = (n & 7) << 4;

    #define COMPUTE(buf)                                                          \
        _Pragma("unroll")                                                         \
        for (int s = 0; s < KC / 32; ++s) {                                       \
            const int o0 = (s * 128 + kg * 32) ^ swzA;                            \
            const int4 qa = *reinterpret_cast<const int4*>(                       \
                (const char*)&Wl[buf][rA][0] + o0);                               \
            const int4 qb = *reinterpret_cast<const int4*>(                       \
                (const char*)&Wl[buf][rA][0] + (o0 ^ 16));                        \
            bf16x8 a;                                                             \
            a[0]=bf((float)qa.x); a[1]=bf((float)qa.y);                           \
            a[2]=bf((float)qa.z); a[3]=bf((float)qa.w);                           \
            a[4]=bf((float)qb.x); a[5]=bf((float)qb.y);                           \
            a[6]=bf((float)qb.z); a[7]=bf((float)qb.w);                           \
            const int ox = (s * 64 + kg * 16) ^ swzAx;                            \
            bf16x8 b = *reinterpret_cast<const bf16x8*>(                          \
                (const char*)&Xl[buf][n][0] + ox);                                \
            acc = __builtin_amdgcn_mfma_f32_16x16x32_bf16(a, b, acc, 0, 0, 0);    \
        }

    // ---- prologue: group(0) = X(0) then W(0) ----
    LOADX(0);
    SBAR();
    GLOADW(0, 0);
    SBAR();
    asm volatile("s_waitcnt vmcnt(8)");       // retire X(0); W(0) stays out
    SBAR();
    XWRITE(0);
    SBAR();
    asm volatile("s_waitcnt lgkmcnt(0)");
    SBAR();
    __builtin_amdgcn_s_barrier();             // raw: W(0) 8 loads cross it
    SBAR();

    // ---- main loop ----
    for (int t = 0; t < NT; ++t) {
        const int cur = t & 1;
        if (t + 1 < NT) {
            LOADX(t + 1);
            SBAR();
            GLOADW(cur ^ 1, t + 1);
            SBAR();
            asm volatile("s_waitcnt vmcnt(10)");   // retire W(t) only
        } else {
            asm volatile("s_waitcnt vmcnt(0)");    // tail: drain W(NT-1)
        }
        SBAR();
        COMPUTE(cur);
        SBAR();
        if (t + 1 < NT) {
            asm volatile("s_waitcnt vmcnt(8)");    // retire X(t+1); keep W(t+1)
            SBAR();
            XWRITE(cur ^ 1);
            SBAR();
            asm volatile("s_waitcnt lgkmcnt(0)");
            SBAR();
            __builtin_amdgcn_s_barrier();          // 8 W loads in flight
            SBAR();
        }
    }

    // ---- epilogue: D col = lane&15 (batch n), row = kg*4 + reg (out-ch) ----
    const int o = o_base + wave * 16 + kg * 4;
    const float4 sc = *reinterpret_cast<const float4*>(scale + o);
    const float4 bs = *reinterpret_cast<const float4*>(bias + o);
    float4 rr;
    rr.x = acc[0] * sc.x + bs.x;
    rr.y = acc[1] * sc.y + bs.y;
    rr.z = acc[2] * sc.z + bs.z;
    rr.w = acc[3] * sc.w + bs.w;
    *reinterpret_cast<float4*>(out + (size_t)n * OUT_F + o) = rr;

    #undef LOADX
    #undef GLOADW
    #undef XWRITE
    #undef COMPUTE
}

extern "C" void kernel_launch(void* const* d_in, const int* in_sizes, int n_in,
                              void* d_out, int out_size, void* d_ws, size_t ws_size,
                              hipStream_t stream) {
    const float* x     = (const float*)d_in[0];
    const int*   w     = (const int*)  d_in[1];   // int8 values widened to int32 by harness
    const float* scale = (const float*)d_in[2];
    const float* bias  = (const float*)d_in[3];
    float* out = (float*)d_out;
    (void)in_sizes; (void)n_in; (void)d_ws; (void)ws_size; (void)out_size;

    w8a16_kernel<<<dim3(OUT_F / 64), dim3(256), 0, stream>>>(w, x, scale, bias, out);
}

// Round 11
// 93.277 us; speedup vs baseline: 1.1637x; 1.1183x over previous
//
#include <hip/hip_runtime.h>

#define IN_F  4096
#define OUT_F 32000
#define KC    128          // k per tile
#define NT    (IN_F / KC)  // 32 tiles

typedef __attribute__((ext_vector_type(8))) short bf16x8;
typedef __attribute__((ext_vector_type(4))) float f32x4;
typedef unsigned int u32;

__device__ __forceinline__ short bf(float f) {
    __bf16 h = (__bf16)f;
    short s;
    __builtin_memcpy(&s, &h, 2);
    return s;
}

// HBM -> LDS direct (16B/lane). LDS dest = wave-uniform base + lane*16;
// per-lane global source carries the swizzle. (Proven in R7.)
__device__ __forceinline__ void gload16(const void* g, void* l) {
    __builtin_amdgcn_global_load_lds(
        (const __attribute__((address_space(1))) u32*)g,
        (__attribute__((address_space(3))) u32*)l, 16, 0, 0);
}

// W-row swizzle (R7-verified): fragment ds_read_b128 pairs land 8 accesses
// on every one of the 32 banks (conflict-free minimum).
__device__ __forceinline__ int swzW(int r) {
    return ((r & 7) << 5) | (((r >> 3) & 1) << 4);
}

// R7 structure with BM 64->32: block = 2 waves (128 thr), 32 out-ch x 16
// batch, 40 KB LDS -> 4 blocks/CU (vs R7's 2), grid 1000. Same 8 waves/CU
// but in 4 independent barrier domains with 4 uncoupled prefetch pipelines.
// Everything else identical to R7: W via global_load_lds (raw int32,
// double-buffered, source-pre-swizzled), X reg-staged -> bf16 LDS, X loads
// issued BEFORE W gloads, one __syncthreads per tile, cvt fused in COMPUTE.
__global__ __launch_bounds__(128) void w8a16_kernel(
    const int* __restrict__ W, const float* __restrict__ X,
    const float* __restrict__ scale, const float* __restrict__ bias,
    float* __restrict__ out)
{
    __shared__ __align__(16) int   Wl[2][32][KC];  // raw int32, 32 KB
    __shared__ __align__(16) short Xl[2][16][KC];  // bf16, 8 KB

    const int tid  = threadIdx.x;
    const int lane = tid & 63;
    const int wave = tid >> 6;    // 0..1
    const int n    = lane & 15;   // MFMA: A row (out-ch) / B row (batch)
    const int kg   = lane >> 4;   // MFMA k-group
    const int lo   = lane & 31;   // staging: 16-B quad within 512-B chunk
    const int hi   = lane >> 5;   // staging: row parity within instr
    const int o_base = blockIdx.x * 32;

    float4 xreg[4];
    f32x4  acc = {0.f, 0.f, 0.f, 0.f};

    // X: 4 loads/wave; wave w stages rows 8w..8w+7 (block covers 0..15)
    #define LOADX(t)                                                              \
        _Pragma("unroll")                                                         \
        for (int j = 0; j < 4; ++j) {                                             \
            const int r = wave * 8 + 2 * j + hi;                                  \
            xreg[j] = *reinterpret_cast<const float4*>(                           \
                X + (size_t)r * IN_F + (t) * KC + lo * 4);                        \
        }

    // W: 8 x 1KB gloads/wave; wave w owns rows 16w..16w+15
    #define GLOADW(buf, t)                                                        \
        _Pragma("unroll")                                                         \
        for (int j = 0; j < 8; ++j) {                                             \
            const int r  = wave * 16 + 2 * j + hi;                                \
            const char* gp = (const char*)W                                       \
                + ((size_t)(o_base + r) * IN_F + (size_t)(t) * KC) * 4            \
                + ((lo * 16) ^ swzW(r));                                          \
            gload16(gp, &Wl[buf][wave * 16 + 2 * j][0]);                          \
        }

    #define XWRITE(buf)                                                           \
        _Pragma("unroll")                                                         \
        for (int j = 0; j < 4; ++j) {                                             \
            const int r = wave * 8 + 2 * j + hi;                                  \
            short4 v;                                                             \
            v.x = bf(xreg[j].x); v.y = bf(xreg[j].y);                             \
            v.z = bf(xreg[j].z); v.w = bf(xreg[j].w);                             \
            char* p = (char*)&Xl[buf][r][0] + ((lo * 8) ^ ((r & 7) << 4));        \
            *reinterpret_cast<short4*>(p) = v;                                    \
        }

    const int rA    = wave * 16 + n;
    const int swzA  = swzW(rA);
    const int swzAx = (n & 7) << 4;

    #define COMPUTE(buf)                                                          \
        _Pragma("unroll")                                                         \
        for (int s = 0; s < KC / 32; ++s) {                                       \
            const int o0 = (s * 128 + kg * 32) ^ swzA;                            \
            const int4 qa = *reinterpret_cast<const int4*>(                       \
                (const char*)&Wl[buf][rA][0] + o0);                               \
            const int4 qb = *reinterpret_cast<const int4*>(                       \
                (const char*)&Wl[buf][rA][0] + (o0 ^ 16));                        \
            bf16x8 a;                                                             \
            a[0]=bf((float)qa.x); a[1]=bf((float)qa.y);                           \
            a[2]=bf((float)qa.z); a[3]=bf((float)qa.w);                           \
            a[4]=bf((float)qb.x); a[5]=bf((float)qb.y);                           \
            a[6]=bf((float)qb.z); a[7]=bf((float)qb.w);                           \
            const int ox = (s * 64 + kg * 16) ^ swzAx;                            \
            bf16x8 b = *reinterpret_cast<const bf16x8*>(                          \
                (const char*)&Xl[buf][n][0] + ox);                                \
            acc = __builtin_amdgcn_mfma_f32_16x16x32_bf16(a, b, acc, 0, 0, 0);    \
        }

    // ---- prologue ----
    LOADX(0);
    GLOADW(0, 0);
    XWRITE(0);            // waits only on the 4 X loads (8 W gloads stay out)
    __syncthreads();      // drains tile-0 W into LDS

    // ---- main loop: one barrier per tile ----
    for (int t = 0; t < NT; ++t) {
        const int cur = t & 1;
        if (t + 1 < NT) {
            LOADX(t + 1);
            GLOADW(cur ^ 1, t + 1);   // in flight across COMPUTE(cur)
        }
        COMPUTE(cur);
        if (t + 1 < NT) { XWRITE(cur ^ 1); }
        __syncthreads();
    }

    // ---- epilogue: D col = lane&15 (batch n), row = kg*4 + reg (out-ch) ----
    const int o = o_base + wave * 16 + kg * 4;
    const float4 sc = *reinterpret_cast<const float4*>(scale + o);
    const float4 bs = *reinterpret_cast<const float4*>(bias + o);
    float4 rr;
    rr.x = acc[0] * sc.x + bs.x;
    rr.y = acc[1] * sc.y + bs.y;
    rr.z = acc[2] * sc.z + bs.z;
    rr.w = acc[3] * sc.w + bs.w;
    *reinterpret_cast<float4*>(out + (size_t)n * OUT_F + o) = rr;

    #undef LOADX
    #undef GLOADW
    #undef XWRITE
    #undef COMPUTE
}

extern "C" void kernel_launch(void* const* d_in, const int* in_sizes, int n_in,
                              void* d_out, int out_size, void* d_ws, size_t ws_size,
                              hipStream_t stream) {
    const float* x     = (const float*)d_in[0];
    const int*   w     = (const int*)  d_in[1];   // int8 values widened to int32 by harness
    const float* scale = (const float*)d_in[2];
    const float* bias  = (const float*)d_in[3];
    float* out = (float*)d_out;
    (void)in_sizes; (void)n_in; (void)d_ws; (void)ws_size; (void)out_size;

    w8a16_kernel<<<dim3(OUT_F / 32), dim3(128), 0, stream>>>(w, x, scale, bias, out);
}